// Round 22
// baseline (60.474 us; speedup 1.0000x reference)
//
#include <hip/hip_runtime.h>

#define N_NODES 100000
#define N_EDGES 320000
#define Q 4096
#define HID 128
#define DIN 256
#define EMB_LD 260      // DIN + 4 pad: q-rows land on distinct bank groups
#define NSLOT (3 * Q)   // 12288
#define CAP 64
#define QPB 8
#define KT 32           // k-tile staged in LDS

// ---------------- K1: slot = -1 ----------------
__global__ __launch_bounds__(256) void k_init(int4* __restrict__ slot4) {
    int i = blockIdx.x * 256 + threadIdx.x;
    if (i < N_NODES / 4) slot4[i] = make_int4(-1, -1, -1, -1);
}

// ---------------- K2: claim slots via CAS + zero cnt ----------------
__global__ __launch_bounds__(256) void k_claim(const int* __restrict__ s_idx,
                                               const int* __restrict__ p_idx,
                                               const int* __restrict__ n_idx,
                                               int* __restrict__ slot,
                                               int* __restrict__ cnt) {
    int i = blockIdx.x * 256 + threadIdx.x;   // 0 .. NSLOT-1
    cnt[i] = 0;
    int t = i >> 12;
    int q = i & (Q - 1);
    int node = (t == 0 ? s_idx : (t == 1 ? p_idx : n_idx))[q];
    atomicCAS(&slot[node], -1, i);
}

// ---------------- K3: build per-slot edge lists (int2 = {e, td}) -------
__global__ __launch_bounds__(256) void k_build(
    const int* __restrict__ src, const int* __restrict__ dst,
    const float* __restrict__ bt, const float* __restrict__ node_ts,
    const int* __restrict__ slot, int* __restrict__ cnt,
    int2* __restrict__ edata) {
    int e = blockIdx.x * 256 + threadIdx.x;
    if (e >= N_EDGES) return;
    int sl = slot[dst[e]];
    if (sl < 0) return;
    float td = bt[e] - node_ts[src[e]];
    int pos = atomicAdd(&cnt[sl], 1);
    if (pos < CAP) edata[sl * CAP + pos] = make_int2(e, __float_as_int(td));
}

// ---------------- K4: fused emb-build + predictor ----------------
// 512 blocks x 256 threads (4 waves), 8 queries per block.
// Phase A (gather): wave w owns rows {w, w+4, ..., w+20}; j=lane>>4 edge
//   slot, g=lane&15 col group.
// Phase B (GEMM): W k-tiles staged in LDS via global_load_lds (direct DMA,
//   no register round-trip); thread = 2 queries (qp, qp+4) x 4 cols x 3
//   mats; the two 128-thread halves split each k-tile.
__global__ __launch_bounds__(256) void k_fused(
    const int* __restrict__ s_idx, const int* __restrict__ p_idx,
    const int* __restrict__ n_idx, const int* __restrict__ slot,
    const int* __restrict__ cnt, const int2* __restrict__ edata,
    const float* __restrict__ ef,
    const float* __restrict__ time_w, const float* __restrict__ time_b,
    const float* __restrict__ W_src, const float* __restrict__ b_src,
    const float* __restrict__ W_dst, const float* __restrict__ b_dst,
    const float* __restrict__ W_out, const float* __restrict__ b_out,
    float* __restrict__ out) {
    __shared__ float emb[QPB * 3][EMB_LD];   // ~25 KB (re-used as partials)
    __shared__ float wstage[2][KT][HID];     // 32 KB
    const int tid   = threadIdx.x;
    const int qbase = blockIdx.x * QPB;
    const int w     = tid >> 6;
    const int lane  = tid & 63;

    // ---- Phase A: lane-parallel gather ----
    {
        const int j = lane >> 4;          // edge slot 0..3
        const int g = lane & 15;          // col group 0..15
        const float4 tw0 = *reinterpret_cast<const float4*>(time_w + 8 * g);
        const float4 tw1 = *reinterpret_cast<const float4*>(time_w + 8 * g + 4);
        const float4 tb0 = *reinterpret_cast<const float4*>(time_b + 8 * g);
        const float4 tb1 = *reinterpret_cast<const float4*>(time_b + 8 * g + 4);
        for (int row = w; row < QPB * 3; row += 4) {
            int t = row >> 3, q = row & 7;
            const int* ia = (t == 0) ? s_idx : (t == 1) ? p_idx : n_idx;
            int sl = slot[ia[qbase + q]];
            int n = cnt[sl]; if (n > CAP) n = CAP;
            float4 accA = {0.f, 0.f, 0.f, 0.f}, accB = {0.f, 0.f, 0.f, 0.f};
            float4 tcA  = {0.f, 0.f, 0.f, 0.f}, tcB  = {0.f, 0.f, 0.f, 0.f};
            for (int jb = j; jb < n; jb += 4) {
                int2 ed = edata[(size_t)sl * CAP + jb];
                const float* rp = ef + (size_t)ed.x * 128;
                float4 vA = *reinterpret_cast<const float4*>(rp + 4 * g);
                float4 vB = *reinterpret_cast<const float4*>(rp + 64 + 4 * g);
                float td = __int_as_float(ed.y);
                accA.x += vA.x; accA.y += vA.y; accA.z += vA.z; accA.w += vA.w;
                accB.x += vB.x; accB.y += vB.y; accB.z += vB.z; accB.w += vB.w;
                tcA.x += __cosf(td * tw0.x + tb0.x);
                tcA.y += __cosf(td * tw0.y + tb0.y);
                tcA.z += __cosf(td * tw0.z + tb0.z);
                tcA.w += __cosf(td * tw0.w + tb0.w);
                tcB.x += __cosf(td * tw1.x + tb1.x);
                tcB.y += __cosf(td * tw1.y + tb1.y);
                tcB.z += __cosf(td * tw1.z + tb1.z);
                tcB.w += __cosf(td * tw1.w + tb1.w);
            }
#define RED2(v) { v += __shfl_xor(v, 16); v += __shfl_xor(v, 32); }
            RED2(accA.x) RED2(accA.y) RED2(accA.z) RED2(accA.w)
            RED2(accB.x) RED2(accB.y) RED2(accB.z) RED2(accB.w)
            RED2(tcA.x)  RED2(tcA.y)  RED2(tcA.z)  RED2(tcA.w)
            RED2(tcB.x)  RED2(tcB.y)  RED2(tcB.z)  RED2(tcB.w)
#undef RED2
            if (j == 0) {
                *reinterpret_cast<float4*>(&emb[row][4 * g])       = accA;
                *reinterpret_cast<float4*>(&emb[row][64 + 4 * g])  = accB;
                *reinterpret_cast<float4*>(&emb[row][128 + 8 * g]) = tcA;
                *reinterpret_cast<float4*>(&emb[row][132 + 8 * g]) = tcB;
            }
        }
    }

    // ---- Phase B: GEMM, thread = 2 queries x 4 cols; halves split k ----
    const int half    = tid >> 7;         // 0,1
    const int hid     = tid & 127;
    const int qp      = hid >> 5;         // 0..3 -> queries qp, qp+4
    const int g2      = hid & 31;         // 0..31
    const int colbase = g2 << 2;          // 0..124

    float aS0[4], aS1[4], aP0[4], aP1[4], aN0[4], aN1[4];
    {
        float4 bs = *reinterpret_cast<const float4*>(b_src + colbase);
        float4 bd = *reinterpret_cast<const float4*>(b_dst + colbase);
        #pragma unroll
        for (int c = 0; c < 4; ++c) {
            float bsc = half ? 0.f : (&bs.x)[c];
            float bdc = half ? 0.f : (&bd.x)[c];
            aS0[c] = bsc; aS1[c] = bsc;
            aP0[c] = bdc; aP1[c] = bdc;
            aN0[c] = bdc; aN1[c] = bdc;
        }
    }

    const float* e_s0 = emb[qp];
    const float* e_s1 = emb[qp + 4];
    const float* e_p0 = emb[QPB + qp];
    const float* e_p1 = emb[QPB + qp + 4];
    const float* e_n0 = emb[2 * QPB + qp];
    const float* e_n1 = emb[2 * QPB + qp + 4];

    for (int kt = 0; kt < DIN; kt += KT) {
        __syncthreads();   // Phase A done (kt=0) / previous tile consumed
        // stage W via global_load_lds: 32 chunks of 1 KB (2 k-rows each);
        // wave w issues chunks w*8 .. w*8+7. LDS base wave-uniform,
        // per-lane global src contiguous (lane*16 B).
        {
            const int c0 = w * 8;
            #pragma unroll
            for (int i = 0; i < 8; ++i) {
                int c   = c0 + i;
                int mat = c >> 4;             // 0..1
                int k2  = (c & 15) * 2;       // 0,2,..,30
                const float* gp = (mat ? W_dst : W_src)
                                  + (size_t)(kt + k2) * HID + lane * 4;
                __builtin_amdgcn_global_load_lds(
                    (const __attribute__((address_space(1))) void*)gp,
                    (__attribute__((address_space(3))) void*)&wstage[mat][k2][0],
                    16, 0, 0);
            }
        }
        __syncthreads();   // vmcnt drained by compiler before barrier
        const int lk0 = half * (KT / 2);          // 0 or 16
        const int kb  = kt + lk0;
        for (int kk = 0; kk < KT / 2; kk += 4) {
            float4 s0 = *reinterpret_cast<const float4*>(e_s0 + kb + kk);
            float4 s1 = *reinterpret_cast<const float4*>(e_s1 + kb + kk);
            float4 p0 = *reinterpret_cast<const float4*>(e_p0 + kb + kk);
            float4 p1 = *reinterpret_cast<const float4*>(e_p1 + kb + kk);
            float4 n0 = *reinterpret_cast<const float4*>(e_n0 + kb + kk);
            float4 n1 = *reinterpret_cast<const float4*>(e_n1 + kb + kk);
            #pragma unroll
            for (int k4 = 0; k4 < 4; ++k4) {
                float4 ws = *reinterpret_cast<const float4*>(&wstage[0][lk0 + kk + k4][colbase]);
                float4 wd = *reinterpret_cast<const float4*>(&wstage[1][lk0 + kk + k4][colbase]);
                float sv0 = (&s0.x)[k4], sv1 = (&s1.x)[k4];
                float pv0 = (&p0.x)[k4], pv1 = (&p1.x)[k4];
                float nv0 = (&n0.x)[k4], nv1 = (&n1.x)[k4];
                #pragma unroll
                for (int c = 0; c < 4; ++c) {
                    float wsc = (&ws.x)[c], wdc = (&wd.x)[c];
                    aS0[c] += sv0 * wsc;  aS1[c] += sv1 * wsc;
                    aP0[c] += pv0 * wdc;  aP1[c] += pv1 * wdc;
                    aN0[c] += nv0 * wdc;  aN1[c] += nv1 * wdc;
                }
            }
        }
    }

    // ---- merge halves via LDS overlay on emb, then relu + W_out dot ----
    float (*part)[24] = reinterpret_cast<float(*)[24]>(&emb[0][0]);  // 128x24
    __syncthreads();                      // all emb reads done
    if (half) {
        float* p = part[hid];
        #pragma unroll
        for (int c = 0; c < 4; ++c) {
            p[c]      = aS0[c]; p[4 + c]  = aS1[c];
            p[8 + c]  = aP0[c]; p[12 + c] = aP1[c];
            p[16 + c] = aN0[c]; p[20 + c] = aN1[c];
        }
    }
    __syncthreads();
    if (!half) {
        const float* p = part[hid];
        float4 wo = *reinterpret_cast<const float4*>(W_out + colbase);
        float rP0 = 0.f, rN0 = 0.f, rP1 = 0.f, rN1 = 0.f;
        #pragma unroll
        for (int c = 0; c < 4; ++c) {
            float sc0 = aS0[c] + p[c],      sc1 = aS1[c] + p[4 + c];
            float pc0 = aP0[c] + p[8 + c],  pc1 = aP1[c] + p[12 + c];
            float nc0 = aN0[c] + p[16 + c], nc1 = aN1[c] + p[20 + c];
            float woc = (&wo.x)[c];
            rP0 += fmaxf(sc0 + pc0, 0.f) * woc;
            rN0 += fmaxf(sc0 + nc0, 0.f) * woc;
            rP1 += fmaxf(sc1 + pc1, 0.f) * woc;
            rN1 += fmaxf(sc1 + nc1, 0.f) * woc;
        }
        #pragma unroll
        for (int off = 1; off < 32; off <<= 1) {
            rP0 += __shfl_xor(rP0, off);
            rN0 += __shfl_xor(rN0, off);
            rP1 += __shfl_xor(rP1, off);
            rN1 += __shfl_xor(rN1, off);
        }
        if (g2 == 0) {
            float bo = b_out[0];
            out[qbase + qp]         = rP0 + bo;
            out[Q + qbase + qp]     = rN0 + bo;
            out[qbase + qp + 4]     = rP1 + bo;
            out[Q + qbase + qp + 4] = rN1 + bo;
        }
    }
}

// ---------------- launch ----------------

extern "C" void kernel_launch(void* const* d_in, const int* in_sizes, int n_in,
                              void* d_out, int out_size, void* d_ws, size_t ws_size,
                              hipStream_t stream) {
    const int*   src     = (const int*)d_in[0];
    const int*   dst     = (const int*)d_in[1];
    const float* ef      = (const float*)d_in[2];
    const float* bt      = (const float*)d_in[3];
    const float* node_ts = (const float*)d_in[4];
    const int*   s_idx   = (const int*)d_in[5];
    const int*   p_idx   = (const int*)d_in[6];
    const int*   n_idx   = (const int*)d_in[7];
    const float* time_w  = (const float*)d_in[8];
    const float* time_b  = (const float*)d_in[9];
    const float* W_src   = (const float*)d_in[10];
    const float* b_src   = (const float*)d_in[11];
    const float* W_dst   = (const float*)d_in[12];
    const float* b_dst   = (const float*)d_in[13];
    const float* W_out   = (const float*)d_in[14];
    const float* b_out   = (const float*)d_in[15];
    float*       out     = (float*)d_out;

    // workspace layout (bytes)
    char* ws = (char*)d_ws;
    int*   slot  = (int*)ws;                          // [100000]
    int*   cnt   = (int*)(ws + 512 * 1024);           // [12288]
    int2*  edata = (int2*)(ws + 1024 * 1024);         // [12288*64] int2 = 6.3 MB

    k_init<<<(N_NODES / 4 + 255) / 256, 256, 0, stream>>>((int4*)slot);
    k_claim<<<NSLOT / 256, 256, 0, stream>>>(s_idx, p_idx, n_idx, slot, cnt);
    k_build<<<(N_EDGES + 255) / 256, 256, 0, stream>>>(src, dst, bt, node_ts,
                                                       slot, cnt, edata);
    k_fused<<<Q / QPB, 256, 0, stream>>>(s_idx, p_idx, n_idx, slot, cnt,
                                         edata, ef, time_w, time_b,
                                         W_src, b_src, W_dst, b_dst,
                                         W_out, b_out, out);
}

// Round 23
// 48.913 us; speedup vs baseline: 1.2364x; 1.2364x over previous
//
#include <hip/hip_runtime.h>

#define N_NODES 100000
#define N_EDGES 320000
#define Q 4096
#define HID 128
#define DIN 256
#define EMB_LD 260      // DIN + 4 pad: q-rows land on distinct bank groups
#define NSLOT (3 * Q)   // 12288
#define CAP 64
#define QPB 8
#define KT 32           // k-tile staged in LDS

// ---------------- K1: slot = -1 ----------------
__global__ __launch_bounds__(256) void k_init(int4* __restrict__ slot4) {
    int i = blockIdx.x * 256 + threadIdx.x;
    if (i < N_NODES / 4) slot4[i] = make_int4(-1, -1, -1, -1);
}

// ---------------- K2: claim slots via CAS + zero cnt ----------------
__global__ __launch_bounds__(256) void k_claim(const int* __restrict__ s_idx,
                                               const int* __restrict__ p_idx,
                                               const int* __restrict__ n_idx,
                                               int* __restrict__ slot,
                                               int* __restrict__ cnt) {
    int i = blockIdx.x * 256 + threadIdx.x;   // 0 .. NSLOT-1
    cnt[i] = 0;
    int t = i >> 12;
    int q = i & (Q - 1);
    int node = (t == 0 ? s_idx : (t == 1 ? p_idx : n_idx))[q];
    atomicCAS(&slot[node], -1, i);
}

// ---------------- K3: build per-slot edge lists (int2 = {e, td}) -------
__global__ __launch_bounds__(256) void k_build(
    const int* __restrict__ src, const int* __restrict__ dst,
    const float* __restrict__ bt, const float* __restrict__ node_ts,
    const int* __restrict__ slot, int* __restrict__ cnt,
    int2* __restrict__ edata) {
    int e = blockIdx.x * 256 + threadIdx.x;
    if (e >= N_EDGES) return;
    int sl = slot[dst[e]];
    if (sl < 0) return;
    float td = bt[e] - node_ts[src[e]];
    int pos = atomicAdd(&cnt[sl], 1);
    if (pos < CAP) edata[sl * CAP + pos] = make_int2(e, __float_as_int(td));
}

// ---------------- K4: fused emb-build + predictor ----------------
// 512 blocks x 256 threads (4 waves), 8 queries per block.
// Phase A (gather): wave w owns rows {w, w+4, ..., w+20}; j=lane>>4 edge
//   slot, g=lane&15 col group.
// Phase B (GEMM): W k-tiles staged in LDS; thread = 2 queries (qp, qp+4)
//   x 4 cols x 3 mats; the two 128-thread halves split each k-tile.
__global__ __launch_bounds__(256) void k_fused(
    const int* __restrict__ s_idx, const int* __restrict__ p_idx,
    const int* __restrict__ n_idx, const int* __restrict__ slot,
    const int* __restrict__ cnt, const int2* __restrict__ edata,
    const float* __restrict__ ef,
    const float* __restrict__ time_w, const float* __restrict__ time_b,
    const float* __restrict__ W_src, const float* __restrict__ b_src,
    const float* __restrict__ W_dst, const float* __restrict__ b_dst,
    const float* __restrict__ W_out, const float* __restrict__ b_out,
    float* __restrict__ out) {
    __shared__ float emb[QPB * 3][EMB_LD];   // ~25 KB (re-used as partials)
    __shared__ float wstage[2][KT][HID];     // 32 KB
    const int tid   = threadIdx.x;
    const int qbase = blockIdx.x * QPB;
    const int w     = tid >> 6;
    const int lane  = tid & 63;

    // ---- Phase A: lane-parallel gather ----
    {
        const int j = lane >> 4;          // edge slot 0..3
        const int g = lane & 15;          // col group 0..15
        const float4 tw0 = *reinterpret_cast<const float4*>(time_w + 8 * g);
        const float4 tw1 = *reinterpret_cast<const float4*>(time_w + 8 * g + 4);
        const float4 tb0 = *reinterpret_cast<const float4*>(time_b + 8 * g);
        const float4 tb1 = *reinterpret_cast<const float4*>(time_b + 8 * g + 4);
        for (int row = w; row < QPB * 3; row += 4) {
            int t = row >> 3, q = row & 7;
            const int* ia = (t == 0) ? s_idx : (t == 1) ? p_idx : n_idx;
            int sl = slot[ia[qbase + q]];
            int n = cnt[sl]; if (n > CAP) n = CAP;
            float4 accA = {0.f, 0.f, 0.f, 0.f}, accB = {0.f, 0.f, 0.f, 0.f};
            float4 tcA  = {0.f, 0.f, 0.f, 0.f}, tcB  = {0.f, 0.f, 0.f, 0.f};
            for (int jb = j; jb < n; jb += 4) {
                int2 ed = edata[(size_t)sl * CAP + jb];
                const float* rp = ef + (size_t)ed.x * 128;
                float4 vA = *reinterpret_cast<const float4*>(rp + 4 * g);
                float4 vB = *reinterpret_cast<const float4*>(rp + 64 + 4 * g);
                float td = __int_as_float(ed.y);
                accA.x += vA.x; accA.y += vA.y; accA.z += vA.z; accA.w += vA.w;
                accB.x += vB.x; accB.y += vB.y; accB.z += vB.z; accB.w += vB.w;
                tcA.x += __cosf(td * tw0.x + tb0.x);
                tcA.y += __cosf(td * tw0.y + tb0.y);
                tcA.z += __cosf(td * tw0.z + tb0.z);
                tcA.w += __cosf(td * tw0.w + tb0.w);
                tcB.x += __cosf(td * tw1.x + tb1.x);
                tcB.y += __cosf(td * tw1.y + tb1.y);
                tcB.z += __cosf(td * tw1.z + tb1.z);
                tcB.w += __cosf(td * tw1.w + tb1.w);
            }
#define RED2(v) { v += __shfl_xor(v, 16); v += __shfl_xor(v, 32); }
            RED2(accA.x) RED2(accA.y) RED2(accA.z) RED2(accA.w)
            RED2(accB.x) RED2(accB.y) RED2(accB.z) RED2(accB.w)
            RED2(tcA.x)  RED2(tcA.y)  RED2(tcA.z)  RED2(tcA.w)
            RED2(tcB.x)  RED2(tcB.y)  RED2(tcB.z)  RED2(tcB.w)
#undef RED2
            if (j == 0) {
                *reinterpret_cast<float4*>(&emb[row][4 * g])       = accA;
                *reinterpret_cast<float4*>(&emb[row][64 + 4 * g])  = accB;
                *reinterpret_cast<float4*>(&emb[row][128 + 8 * g]) = tcA;
                *reinterpret_cast<float4*>(&emb[row][132 + 8 * g]) = tcB;
            }
        }
    }

    // ---- Phase B: GEMM, thread = 2 queries x 4 cols; halves split k ----
    const int half    = tid >> 7;         // 0,1
    const int hid     = tid & 127;
    const int qp      = hid >> 5;         // 0..3 -> queries qp, qp+4
    const int g2      = hid & 31;         // 0..31
    const int colbase = g2 << 2;          // 0..124

    float aS0[4], aS1[4], aP0[4], aP1[4], aN0[4], aN1[4];
    {
        float4 bs = *reinterpret_cast<const float4*>(b_src + colbase);
        float4 bd = *reinterpret_cast<const float4*>(b_dst + colbase);
        #pragma unroll
        for (int c = 0; c < 4; ++c) {
            float bsc = half ? 0.f : (&bs.x)[c];
            float bdc = half ? 0.f : (&bd.x)[c];
            aS0[c] = bsc; aS1[c] = bsc;
            aP0[c] = bdc; aP1[c] = bdc;
            aN0[c] = bdc; aN1[c] = bdc;
        }
    }

    const float* e_s0 = emb[qp];
    const float* e_s1 = emb[qp + 4];
    const float* e_p0 = emb[QPB + qp];
    const float* e_p1 = emb[QPB + qp + 4];
    const float* e_n0 = emb[2 * QPB + qp];
    const float* e_n1 = emb[2 * QPB + qp + 4];

    for (int kt = 0; kt < DIN; kt += KT) {
        __syncthreads();   // Phase A done (kt=0) / previous tile consumed
        // stage W_src/W_dst[kt:kt+KT][0:128]: 2048 float4, 8 per thread
        for (int r = tid; r < 2 * KT * HID / 4; r += 256) {
            int mat = r >> 10;            // 0..1
            int rem = r & 1023;
            int k   = rem >> 5;           // 0..31
            int c4  = rem & 31;           // 0..31
            const float* Wp = mat ? W_dst : W_src;
            float4 v = *reinterpret_cast<const float4*>(
                Wp + (size_t)(kt + k) * HID + c4 * 4);
            *reinterpret_cast<float4*>(&wstage[mat][k][c4 * 4]) = v;
        }
        __syncthreads();
        const int lk0 = half * (KT / 2);          // 0 or 16
        const int kb  = kt + lk0;
        for (int kk = 0; kk < KT / 2; kk += 4) {
            float4 s0 = *reinterpret_cast<const float4*>(e_s0 + kb + kk);
            float4 s1 = *reinterpret_cast<const float4*>(e_s1 + kb + kk);
            float4 p0 = *reinterpret_cast<const float4*>(e_p0 + kb + kk);
            float4 p1 = *reinterpret_cast<const float4*>(e_p1 + kb + kk);
            float4 n0 = *reinterpret_cast<const float4*>(e_n0 + kb + kk);
            float4 n1 = *reinterpret_cast<const float4*>(e_n1 + kb + kk);
            #pragma unroll
            for (int k4 = 0; k4 < 4; ++k4) {
                float4 ws = *reinterpret_cast<const float4*>(&wstage[0][lk0 + kk + k4][colbase]);
                float4 wd = *reinterpret_cast<const float4*>(&wstage[1][lk0 + kk + k4][colbase]);
                float sv0 = (&s0.x)[k4], sv1 = (&s1.x)[k4];
                float pv0 = (&p0.x)[k4], pv1 = (&p1.x)[k4];
                float nv0 = (&n0.x)[k4], nv1 = (&n1.x)[k4];
                #pragma unroll
                for (int c = 0; c < 4; ++c) {
                    float wsc = (&ws.x)[c], wdc = (&wd.x)[c];
                    aS0[c] += sv0 * wsc;  aS1[c] += sv1 * wsc;
                    aP0[c] += pv0 * wdc;  aP1[c] += pv1 * wdc;
                    aN0[c] += nv0 * wdc;  aN1[c] += nv1 * wdc;
                }
            }
        }
    }

    // ---- merge halves via LDS overlay on emb, then relu + W_out dot ----
    float (*part)[24] = reinterpret_cast<float(*)[24]>(&emb[0][0]);  // 128x24
    __syncthreads();                      // all emb reads done
    if (half) {
        float* p = part[hid];
        #pragma unroll
        for (int c = 0; c < 4; ++c) {
            p[c]      = aS0[c]; p[4 + c]  = aS1[c];
            p[8 + c]  = aP0[c]; p[12 + c] = aP1[c];
            p[16 + c] = aN0[c]; p[20 + c] = aN1[c];
        }
    }
    __syncthreads();
    if (!half) {
        const float* p = part[hid];
        float4 wo = *reinterpret_cast<const float4*>(W_out + colbase);
        float rP0 = 0.f, rN0 = 0.f, rP1 = 0.f, rN1 = 0.f;
        #pragma unroll
        for (int c = 0; c < 4; ++c) {
            float sc0 = aS0[c] + p[c],      sc1 = aS1[c] + p[4 + c];
            float pc0 = aP0[c] + p[8 + c],  pc1 = aP1[c] + p[12 + c];
            float nc0 = aN0[c] + p[16 + c], nc1 = aN1[c] + p[20 + c];
            float woc = (&wo.x)[c];
            rP0 += fmaxf(sc0 + pc0, 0.f) * woc;
            rN0 += fmaxf(sc0 + nc0, 0.f) * woc;
            rP1 += fmaxf(sc1 + pc1, 0.f) * woc;
            rN1 += fmaxf(sc1 + nc1, 0.f) * woc;
        }
        #pragma unroll
        for (int off = 1; off < 32; off <<= 1) {
            rP0 += __shfl_xor(rP0, off);
            rN0 += __shfl_xor(rN0, off);
            rP1 += __shfl_xor(rP1, off);
            rN1 += __shfl_xor(rN1, off);
        }
        if (g2 == 0) {
            float bo = b_out[0];
            out[qbase + qp]         = rP0 + bo;
            out[Q + qbase + qp]     = rN0 + bo;
            out[qbase + qp + 4]     = rP1 + bo;
            out[Q + qbase + qp + 4] = rN1 + bo;
        }
    }
}

// ---------------- launch ----------------

extern "C" void kernel_launch(void* const* d_in, const int* in_sizes, int n_in,
                              void* d_out, int out_size, void* d_ws, size_t ws_size,
                              hipStream_t stream) {
    const int*   src     = (const int*)d_in[0];
    const int*   dst     = (const int*)d_in[1];
    const float* ef      = (const float*)d_in[2];
    const float* bt      = (const float*)d_in[3];
    const float* node_ts = (const float*)d_in[4];
    const int*   s_idx   = (const int*)d_in[5];
    const int*   p_idx   = (const int*)d_in[6];
    const int*   n_idx   = (const int*)d_in[7];
    const float* time_w  = (const float*)d_in[8];
    const float* time_b  = (const float*)d_in[9];
    const float* W_src   = (const float*)d_in[10];
    const float* b_src   = (const float*)d_in[11];
    const float* W_dst   = (const float*)d_in[12];
    const float* b_dst   = (const float*)d_in[13];
    const float* W_out   = (const float*)d_in[14];
    const float* b_out   = (const float*)d_in[15];
    float*       out     = (float*)d_out;

    // workspace layout (bytes)
    char* ws = (char*)d_ws;
    int*   slot  = (int*)ws;                          // [100000]
    int*   cnt   = (int*)(ws + 512 * 1024);           // [12288]
    int2*  edata = (int2*)(ws + 1024 * 1024);         // [12288*64] int2 = 6.3 MB

    k_init<<<(N_NODES / 4 + 255) / 256, 256, 0, stream>>>((int4*)slot);
    k_claim<<<NSLOT / 256, 256, 0, stream>>>(s_idx, p_idx, n_idx, slot, cnt);
    k_build<<<(N_EDGES + 255) / 256, 256, 0, stream>>>(src, dst, bt, node_ts,
                                                       slot, cnt, edata);
    k_fused<<<Q / QPB, 256, 0, stream>>>(s_idx, p_idx, n_idx, slot, cnt,
                                         edata, ef, time_w, time_b,
                                         W_src, b_src, W_dst, b_dst,
                                         W_out, b_out, out);
}